// Round 11
// baseline (371.863 us; speedup 1.0000x reference)
//
#include <hip/hip_runtime.h>
#include <math.h>

#define NN 100000
#define NE 1250000
#define DIN 64
#define DHID 128
#define DO2 64   // concat(mu|lv)
#define DOUT 32

#define NBIN 256
#define BINW ((NN + NBIN - 1) / NBIN)   // 391
#define PADW2 2752                      // >= 7 (align residue) + 7*BINW (2737), multiple of 8
#define P1_THREADS 1024
#define P1_EPT 8
#define P1_EPB (P1_THREADS * P1_EPT)    // 8192

typedef unsigned int uint;
typedef unsigned short ushort;

__device__ __forceinline__ ushort f2bf(float f) {
    uint u = __float_as_uint(f);
    uint r = (u + 0x7fffu + ((u >> 16) & 1u)) >> 16;   // RNE
    return (ushort)r;
}
__device__ __forceinline__ uint pack2(float a, float b) {
    return (uint)f2bf(a) | ((uint)f2bf(b) << 16);
}
__device__ __forceinline__ float bflo(uint p) { return __uint_as_float(p << 16); }
__device__ __forceinline__ float bfhi(uint p) { return __uint_as_float(p & 0xffff0000u); }

// ---------- small helpers ----------
__global__ void zero_arr(int* a, int n) {
    int i = blockIdx.x * blockDim.x + threadIdx.x;
    if (i < n) a[i] = 0;
}

// cast + pre-scale: xsb[v] = bf16(dis_v * x[v]); row NN = 0 (padding target)
__global__ void cast_x(const float* __restrict__ x, const float* __restrict__ dis,
                       uint* __restrict__ xb, int npairs) {
    int i = blockIdx.x * blockDim.x + threadIdx.x;
    if (i < npairs) {
        int row = i >> 5;
        if (row < NN) {
            float dv = dis[row];
            float2 v = ((const float2*)x)[i];
            xb[i] = pack2(dv * v.x, dv * v.y);
        } else xb[i] = 0;
    }
}

// ---------- coarse-bin histogram ----------
__global__ __launch_bounds__(P1_THREADS) void bin_hist(const int* __restrict__ dst,
                                                       int* __restrict__ binhist, int n) {
    __shared__ int hist[NBIN];
    int tid = threadIdx.x;
    if (tid < NBIN) hist[tid] = 0;
    __syncthreads();
    int base = blockIdx.x * P1_EPB;
#pragma unroll
    for (int j = 0; j < P1_EPT; j++) {
        int i = base + j * P1_THREADS + tid;
        if (i < n) atomicAdd(&hist[dst[i] / BINW], 1);
    }
    __syncthreads();
    if (tid < NBIN) {
        int v = hist[tid];
        if (v) atomicAdd(&binhist[tid], v);
    }
}

// ---------- scan 256 bin counts -> binoff (exclusive) + init bincur ----------
__global__ __launch_bounds__(NBIN) void bin_scan(const int* __restrict__ binhist,
                                                 int* __restrict__ binoff,
                                                 int* __restrict__ bincur) {
    __shared__ int buf[NBIN];
    int tid = threadIdx.x;
    int v = binhist[tid];
    buf[tid] = v;
    __syncthreads();
    for (int off = 1; off < NBIN; off <<= 1) {
        int t = (tid >= off) ? buf[tid - off] : 0;
        __syncthreads();
        buf[tid] += t;
        __syncthreads();
    }
    int ex = buf[tid] - v;
    binoff[tid] = ex;
    bincur[tid] = ex;
    if (tid == NBIN - 1) binoff[NBIN] = buf[tid];   // = NE
}

// pass 1: block-local counting-sort into 256 coarse bins; packed (src<<9)|localdst
__global__ __launch_bounds__(P1_THREADS) void scatter_pass1(const int* __restrict__ src,
                                                            const int* __restrict__ dst,
                                                            int* __restrict__ bincur,
                                                            uint* __restrict__ ebin, int n) {
    __shared__ int hist[NBIN];
    __shared__ int gbase[NBIN];
    int tid = threadIdx.x;
    if (tid < NBIN) hist[tid] = 0;
    __syncthreads();
    int base = blockIdx.x * P1_EPB;
    uint e[P1_EPT];
    int  rk[P1_EPT];
    int  bn[P1_EPT];
#pragma unroll
    for (int j = 0; j < P1_EPT; j++) {
        int i = base + j * P1_THREADS + tid;
        if (i < n) {
            int d = dst[i];
            int b = d / BINW;
            e[j] = ((uint)src[i] << 9) | (uint)(d - b * BINW);
            bn[j] = b;
            rk[j] = atomicAdd(&hist[b], 1);
        } else bn[j] = -1;
    }
    __syncthreads();
    if (tid < NBIN) gbase[tid] = hist[tid] ? atomicAdd(&bincur[tid], hist[tid]) : 0;
    __syncthreads();
#pragma unroll
    for (int j = 0; j < P1_EPT; j++)
        if (bn[j] >= 0) ebin[gbase[bn[j]] + rk[j]] = e[j];
}

// ---------- per-bin finalize: node hist -> dis + 8-aligned padded offsets + scatter ----------
__global__ __launch_bounds__(256) void bin_finalize(const uint* __restrict__ ebin,
                                                    const int* __restrict__ binoff,
                                                    float* __restrict__ dis,
                                                    int* __restrict__ poffsets,
                                                    int* __restrict__ esrc) {
    __shared__ int hh[BINW];      // hist, then padded inclusive scan
    __shared__ int base_s[BINW];
    __shared__ int cur_s[BINW];
    int b = blockIdx.x;
    int tid = threadIdx.x;
    int v0 = b * BINW;
    int nv = min(BINW, NN - v0);
    int beg = binoff[b], end = binoff[b + 1];
    int pbase = ((beg + 7) & ~7) + PADW2 * b;      // 8-aligned closed-form bin base
    for (int i = tid; i < nv; i += 256) { hh[i] = 0; cur_s[i] = 0; }
    __syncthreads();
    for (int i = beg + tid; i < end; i += 256)
        atomicAdd(&hh[ebin[i] & 511u], 1);
    __syncthreads();
    int i1 = tid + 256;
    int c0 = (tid < nv) ? hh[tid] : 0;  int p0 = (c0 + 7) & ~7;
    int c1 = (i1 < nv) ? hh[i1] : 0;    int p1 = (c1 + 7) & ~7;
    __syncthreads();
    if (tid < nv) hh[tid] = p0;
    if (i1 < nv) hh[i1] = p1;
    __syncthreads();
    for (int off = 1; off < BINW; off <<= 1) {
        int t0 = (tid < nv && tid >= off) ? hh[tid - off] : 0;
        int t1 = (i1 < nv && i1 >= off) ? hh[i1 - off] : 0;
        __syncthreads();
        if (tid < nv) hh[tid] += t0;
        if (i1 < nv) hh[i1] += t1;
        __syncthreads();
    }
    if (tid < nv) {
        int base = pbase + hh[tid] - p0;
        base_s[tid] = base;
        poffsets[v0 + tid] = base;
        dis[v0 + tid] = rsqrtf((float)c0 + 1.0f);
        for (int j = c0; j < p0; j++) esrc[base + j] = NN;   // node tail padding
    }
    if (i1 < nv) {
        int base = pbase + hh[i1] - p1;
        base_s[i1] = base;
        poffsets[v0 + i1] = base;
        dis[v0 + i1] = rsqrtf((float)c1 + 1.0f);
        for (int j = c1; j < p1; j++) esrc[base + j] = NN;
    }
    __syncthreads();
    int binpadend = pbase + hh[nv - 1];                       // 8-aligned
    int nextpbase = (b < NBIN - 1) ? (((end + 7) & ~7) + PADW2 * (b + 1)) : binpadend;
    for (int i = binpadend + tid; i < nextpbase; i += 256) esrc[i] = NN;  // 8-mult gap fill
    if (b == NBIN - 1 && tid == 0) poffsets[NN] = binpadend;
    // scatter (ebin region is L1/L2-hot from the hist pass)
    for (int i = beg + tid; i < end; i += 256) {
        uint e = ebin[i];
        int l = (int)(e & 511u);
        int pos = base_s[l] + atomicAdd(&cur_s[l], 1);
        esrc[pos] = (int)(e >> 9);
    }
}

__global__ void build_wcat(const float* __restrict__ Wmu, const float* __restrict__ Wlv,
                           float* __restrict__ Wcat) {
    int i = blockIdx.x * blockDim.x + threadIdx.x;  // 128*64
    if (i < DHID * DO2) {
        int k = i >> 6, j = i & 63;
        Wcat[i] = (j < DOUT) ? Wmu[k * DOUT + j] : Wlv[k * DOUT + (j - DOUT)];
    }
}

// ---------- aggregateX: axb[v] = bf16( dis_v * (sum_e xsb[s] + xsb[v]) ), branch-free
__global__ __launch_bounds__(256) void aggregateX(const uint* __restrict__ xsb,  // bf16x2 [N+1,32]
                                                  const int* __restrict__ poffsets,
                                                  const int* __restrict__ esrc,
                                                  const float* __restrict__ dis,
                                                  uint* __restrict__ axb) {
    int wave = threadIdx.x >> 6;
    int lane = threadIdx.x & 63;
    int oct  = lane >> 3;
    int j4   = (lane & 7) * 4;
    int v = blockIdx.x * 4 + wave;
    if (v >= NN) return;
    int beg = poffsets[v], end = poffsets[v + 1];
    float a0 = 0.f, a1 = 0.f, a2 = 0.f, a3 = 0.f, a4 = 0.f, a5 = 0.f, a6 = 0.f, a7 = 0.f;
    for (int e0 = beg; e0 < end; e0 += 8) {
        int s = esrc[e0 + oct];
        uint4 p = *(const uint4*)(xsb + (size_t)s * 32 + j4);
        a0 += bflo(p.x); a1 += bfhi(p.x);
        a2 += bflo(p.y); a3 += bfhi(p.y);
        a4 += bflo(p.z); a5 += bfhi(p.z);
        a6 += bflo(p.w); a7 += bfhi(p.w);
    }
#pragma unroll
    for (int m = 8; m < 64; m <<= 1) {
        a0 += __shfl_xor(a0, m); a1 += __shfl_xor(a1, m);
        a2 += __shfl_xor(a2, m); a3 += __shfl_xor(a3, m);
        a4 += __shfl_xor(a4, m); a5 += __shfl_xor(a5, m);
        a6 += __shfl_xor(a6, m); a7 += __shfl_xor(a7, m);
    }
    uint4 pv = *(const uint4*)(xsb + (size_t)v * 32 + j4);   // self-loop (pre-scaled)
    a0 += bflo(pv.x); a1 += bfhi(pv.x);
    a2 += bflo(pv.y); a3 += bfhi(pv.y);
    a4 += bflo(pv.z); a5 += bfhi(pv.z);
    a6 += bflo(pv.w); a7 += bfhi(pv.w);
    if (lane < 8) {
        float dv = dis[v];
        uint4 o;
        o.x = pack2(dv * a0, dv * a1);
        o.y = pack2(dv * a2, dv * a3);
        o.z = pack2(dv * a4, dv * a5);
        o.w = pack2(dv * a6, dv * a7);
        *(uint4*)(axb + (size_t)v * 32 + j4) = o;
    }
}

__device__ __forceinline__ float selu_f(float v) {
    const float scale = 1.0507009873554805f;
    const float alpha = 1.6732632423543772f;
    return scale * (v > 0.f ? v : alpha * (expf(v) - 1.f));
}

// ---------- GEMM1: axb bf16[N,64] @ W1[64,128] + b1, selu -> h bf16[N,128] ----------
__global__ __launch_bounds__(256) void gemm1(const uint* __restrict__ axb,
                                             const float* __restrict__ W,
                                             const float* __restrict__ b,
                                             ushort* __restrict__ out) {
    __shared__ __align__(16) float xT[DIN][64];     // [k][row]  16 KB
    __shared__ __align__(16) float Ws[DIN][DHID];   // 32 KB
    __shared__ __align__(16) float Bs[DHID];
    int tid = threadIdx.x;
    int row0 = blockIdx.x * 64;

    for (int t = tid; t < (DIN * DHID) / 4; t += 256)
        ((float4*)Ws)[t] = ((const float4*)W)[t];
    if (tid < DHID / 4) ((float4*)Bs)[tid] = ((const float4*)b)[tid];

    int rr = tid & 63;
    int kq = tid >> 6;               // 0..3
    int grow = row0 + rr;
    for (int k0 = kq * 8; k0 < DIN; k0 += 32) {
        uint4 pv = make_uint4(0, 0, 0, 0);
        if (grow < NN) pv = *(const uint4*)(axb + (size_t)grow * 32 + k0 / 2);
        xT[k0 + 0][rr] = bflo(pv.x); xT[k0 + 1][rr] = bfhi(pv.x);
        xT[k0 + 2][rr] = bflo(pv.y); xT[k0 + 3][rr] = bfhi(pv.y);
        xT[k0 + 4][rr] = bflo(pv.z); xT[k0 + 5][rr] = bfhi(pv.z);
        xT[k0 + 6][rr] = bflo(pv.w); xT[k0 + 7][rr] = bfhi(pv.w);
    }
    __syncthreads();

    int tx = tid & 31;               // col group
    int ty = tid >> 5;               // 0..7 row group
    int c0 = tx * 4;
    int r0 = ty * 8;
    float acc[8][4];
#pragma unroll
    for (int i = 0; i < 8; i++)
#pragma unroll
        for (int j = 0; j < 4; j++) acc[i][j] = 0.f;

#pragma unroll 4
    for (int k = 0; k < DIN; k++) {
        float4 a0 = *(const float4*)&xT[k][r0];
        float4 a1 = *(const float4*)&xT[k][r0 + 4];
        float4 w  = *(const float4*)&Ws[k][c0];
        float av[8] = {a0.x, a0.y, a0.z, a0.w, a1.x, a1.y, a1.z, a1.w};
        float wv[4] = {w.x, w.y, w.z, w.w};
#pragma unroll
        for (int i = 0; i < 8; i++)
#pragma unroll
            for (int j = 0; j < 4; j++) acc[i][j] += av[i] * wv[j];
    }

    float4 bb = *(const float4*)&Bs[c0];
    float bv[4] = {bb.x, bb.y, bb.z, bb.w};
#pragma unroll
    for (int i = 0; i < 8; i++) {
        int orow = row0 + r0 + i;
        if (orow < NN) {
            float o0 = selu_f(acc[i][0] + bv[0]);
            float o1 = selu_f(acc[i][1] + bv[1]);
            float o2 = selu_f(acc[i][2] + bv[2]);
            float o3 = selu_f(acc[i][3] + bv[3]);
            *(uint2*)(out + (size_t)orow * DHID + c0) = make_uint2(pack2(o0, o1), pack2(o2, o3));
        }
    }
}

// ---------- GEMM2: h bf16[N,128] @ Wcat[128,64], epilogue *dis[v] -> hw2s bf16[N,64] ----------
__global__ __launch_bounds__(256) void gemm2(const ushort* __restrict__ h,
                                             const float* __restrict__ W,
                                             const float* __restrict__ dis,
                                             ushort* __restrict__ out) {
    __shared__ __align__(16) float hsT[DHID][64];   // [k][row] 32 KB
    __shared__ __align__(16) float Ws[DHID][DO2];   // 32 KB
    int tid = threadIdx.x;
    int row0 = blockIdx.x * 64;

    for (int t = tid; t < (DHID * DO2) / 4; t += 256)
        ((float4*)Ws)[t] = ((const float4*)W)[t];

    int rr = tid & 63;
    int kq = tid >> 6;               // 0..3
    int grow = row0 + rr;
    for (int k0 = kq * 8; k0 < DHID; k0 += 32) {
        uint4 pv = make_uint4(0, 0, 0, 0);
        if (grow < NN) pv = *(const uint4*)(h + (size_t)grow * DHID + k0);
        hsT[k0 + 0][rr] = bflo(pv.x); hsT[k0 + 1][rr] = bfhi(pv.x);
        hsT[k0 + 2][rr] = bflo(pv.y); hsT[k0 + 3][rr] = bfhi(pv.y);
        hsT[k0 + 4][rr] = bflo(pv.z); hsT[k0 + 5][rr] = bfhi(pv.z);
        hsT[k0 + 6][rr] = bflo(pv.w); hsT[k0 + 7][rr] = bfhi(pv.w);
    }
    __syncthreads();

    int tx = tid & 15;
    int ty = tid >> 4;               // 0..15
    int c0 = tx * 4;
    int r0 = ty * 4;
    float acc[4][4];
#pragma unroll
    for (int i = 0; i < 4; i++)
#pragma unroll
        for (int j = 0; j < 4; j++) acc[i][j] = 0.f;

#pragma unroll 4
    for (int k = 0; k < DHID; k++) {
        float4 a = *(const float4*)&hsT[k][r0];
        float4 w = *(const float4*)&Ws[k][c0];
        float av[4] = {a.x, a.y, a.z, a.w};
        float wv[4] = {w.x, w.y, w.z, w.w};
#pragma unroll
        for (int i = 0; i < 4; i++)
#pragma unroll
            for (int j = 0; j < 4; j++) acc[i][j] += av[i] * wv[j];
    }

#pragma unroll
    for (int i = 0; i < 4; i++) {
        int orow = row0 + r0 + i;
        if (orow < NN) {
            float dv = dis[orow];
            uint p0 = pack2(dv * acc[i][0], dv * acc[i][1]);
            uint p1 = pack2(dv * acc[i][2], dv * acc[i][3]);
            *(uint2*)(out + (size_t)orow * DO2 + c0) = make_uint2(p0, p1);
        }
    }
}

// ---------- aggregate2: branch-free padded sum; epilogue bias + mu/lv split ----------
__global__ __launch_bounds__(256) void aggregate2(const uint* __restrict__ hw2s, // bf16x2 [N+1,32]
                                                  const int* __restrict__ poffsets,
                                                  const int* __restrict__ esrc,
                                                  const float* __restrict__ dis,
                                                  const float* __restrict__ bmu,
                                                  const float* __restrict__ blv,
                                                  float* __restrict__ out) {
    int wave = threadIdx.x >> 6;
    int lane = threadIdx.x & 63;
    int oct  = lane >> 3;
    int j4   = (lane & 7) * 4;
    int v = blockIdx.x * 4 + wave;
    if (v >= NN) return;
    int beg = poffsets[v], end = poffsets[v + 1];
    float a0 = 0.f, a1 = 0.f, a2 = 0.f, a3 = 0.f, a4 = 0.f, a5 = 0.f, a6 = 0.f, a7 = 0.f;
    for (int e0 = beg; e0 < end; e0 += 8) {
        int s = esrc[e0 + oct];
        uint4 p = *(const uint4*)(hw2s + (size_t)s * 32 + j4);
        a0 += bflo(p.x); a1 += bfhi(p.x);
        a2 += bflo(p.y); a3 += bfhi(p.y);
        a4 += bflo(p.z); a5 += bfhi(p.z);
        a6 += bflo(p.w); a7 += bfhi(p.w);
    }
#pragma unroll
    for (int m = 8; m < 64; m <<= 1) {
        a0 += __shfl_xor(a0, m); a1 += __shfl_xor(a1, m);
        a2 += __shfl_xor(a2, m); a3 += __shfl_xor(a3, m);
        a4 += __shfl_xor(a4, m); a5 += __shfl_xor(a5, m);
        a6 += __shfl_xor(a6, m); a7 += __shfl_xor(a7, m);
    }
    uint4 pv = *(const uint4*)(hw2s + (size_t)v * 32 + j4);  // self-loop (pre-scaled)
    a0 += bflo(pv.x); a1 += bfhi(pv.x);
    a2 += bflo(pv.y); a3 += bfhi(pv.y);
    a4 += bflo(pv.z); a5 += bfhi(pv.z);
    a6 += bflo(pv.w); a7 += bfhi(pv.w);
    if (lane < 8) {
        float dv = dis[v];
        int j = lane;                          // 0..7: feats 8j..8j+7
        const float* bp = (j < 4) ? (bmu + 8 * j) : (blv + 8 * j - 32);
        float* op = (j < 4) ? (out + (size_t)v * DOUT + 8 * j)
                            : (out + (size_t)NN * DOUT + (size_t)v * DOUT + 8 * j - 32);
        float4 b0 = *(const float4*)bp;
        float4 b1 = *(const float4*)(bp + 4);
        *(float4*)op       = make_float4(dv * a0 + b0.x, dv * a1 + b0.y,
                                         dv * a2 + b0.z, dv * a3 + b0.w);
        *(float4*)(op + 4) = make_float4(dv * a4 + b1.x, dv * a5 + b1.y,
                                         dv * a6 + b1.z, dv * a7 + b1.w);
    }
}

extern "C" void kernel_launch(void* const* d_in, const int* in_sizes, int n_in,
                              void* d_out, int out_size, void* d_ws, size_t ws_size,
                              hipStream_t stream) {
    const float* x   = (const float*)d_in[0];
    const int*   ei  = (const int*)d_in[1];
    const int*   e_src = ei;            // edge_index[0]
    const int*   e_dst = ei + NE;       // edge_index[1]
    const float* W1  = (const float*)d_in[2];
    const float* b1  = (const float*)d_in[3];
    const float* Wmu = (const float*)d_in[4];
    const float* bmu = (const float*)d_in[5];
    const float* Wlv = (const float*)d_in[6];
    const float* blv = (const float*)d_in[7];
    float* out = (float*)d_out;

    char* ws = (char*)d_ws;
    size_t off = 0;
    auto alloc = [&](size_t bytes) -> void* {
        void* p = ws + off;
        off += (bytes + 255) & ~(size_t)255;
        return p;
    };
    int*    poffsets  = (int*)alloc((size_t)(NN + 1) * 4);
    int*    esrc      = (int*)alloc((size_t)(NE + (size_t)PADW2 * NBIN + 64) * 4);
    int*    binhist   = (int*)alloc((size_t)NBIN * 4);
    int*    binoff    = (int*)alloc((size_t)(NBIN + 1) * 4);
    int*    bincur    = (int*)alloc((size_t)NBIN * 4);
    float*  dis       = (float*)alloc((size_t)NN * 4);
    float*  Wcat      = (float*)alloc((size_t)DHID * DO2 * 4);
    uint*   xb        = (uint*)alloc((size_t)(NN + 1) * 32 * 4);  // bf16 dis*x + zero row
    uint*   axb       = (uint*)alloc((size_t)NN * 32 * 4);        // bf16 A·x
    ushort* h         = (ushort*)alloc((size_t)NN * DHID * 2);    // bf16 h
    uint*   hw2s      = xb;            // xb dead after aggregateX; row NN stays zero
    uint*   ebin      = (uint*)h;      // h unused until gemm1; 5 MB <= 25.6 MB

    int p1blocks = (NE + P1_EPB - 1) / P1_EPB;
    zero_arr<<<1, NBIN, 0, stream>>>(binhist, NBIN);
    bin_hist<<<p1blocks, P1_THREADS, 0, stream>>>(e_dst, binhist, NE);
    bin_scan<<<1, NBIN, 0, stream>>>(binhist, binoff, bincur);
    scatter_pass1<<<p1blocks, P1_THREADS, 0, stream>>>(e_src, e_dst, bincur, ebin, NE);
    bin_finalize<<<NBIN, 256, 0, stream>>>(ebin, binoff, dis, poffsets, esrc);
    build_wcat<<<(DHID * DO2 + 255) / 256, 256, 0, stream>>>(Wmu, Wlv, Wcat);
    cast_x<<<(((NN + 1) * 32) + 255) / 256, 256, 0, stream>>>(x, dis, xb, (NN + 1) * 32);

    int gblocks = (NN + 63) / 64;
    aggregateX<<<(NN + 3) / 4, 256, 0, stream>>>(xb, poffsets, esrc, dis, axb);
    gemm1<<<gblocks, 256, 0, stream>>>(axb, W1, b1, h);
    gemm2<<<gblocks, 256, 0, stream>>>(h, Wcat, dis, (ushort*)hw2s);
    aggregate2<<<(NN + 3) / 4, 256, 0, stream>>>(hw2s, poffsets, esrc, dis, bmu, blv, out);
}

// Round 12
// 287.266 us; speedup vs baseline: 1.2945x; 1.2945x over previous
//
#include <hip/hip_runtime.h>
#include <math.h>

#define NN 100000
#define NE 1250000
#define DIN 64
#define DHID 128
#define DO2 64   // concat(mu|lv)
#define DOUT 32

#define NBIN 256
#define BINW ((NN + NBIN - 1) / NBIN)   // 391
#define PADW2 2752                      // >= 7 (align residue) + 7*BINW (2737), multiple of 8
#define P1_THREADS 1024
#define P1_EPT 8
#define P1_EPB (P1_THREADS * P1_EPT)    // 8192

typedef unsigned int uint;
typedef unsigned short ushort;

__device__ __forceinline__ ushort f2bf(float f) {
    uint u = __float_as_uint(f);
    uint r = (u + 0x7fffu + ((u >> 16) & 1u)) >> 16;   // RNE
    return (ushort)r;
}
__device__ __forceinline__ uint pack2(float a, float b) {
    return (uint)f2bf(a) | ((uint)f2bf(b) << 16);
}
__device__ __forceinline__ float bflo(uint p) { return __uint_as_float(p << 16); }
__device__ __forceinline__ float bfhi(uint p) { return __uint_as_float(p & 0xffff0000u); }

// ---------- small helpers ----------
__global__ void zero_arr(int* a, int n) {
    int i = blockIdx.x * blockDim.x + threadIdx.x;
    if (i < n) a[i] = 0;
}

// cast + pre-scale: xsb[v] = bf16(dis_v * x[v]); row NN = 0 (padding target)
__global__ void cast_x(const float* __restrict__ x, const float* __restrict__ dis,
                       uint* __restrict__ xb, int npairs) {
    int i = blockIdx.x * blockDim.x + threadIdx.x;
    if (i < npairs) {
        int row = i >> 5;
        if (row < NN) {
            float dv = dis[row];
            float2 v = ((const float2*)x)[i];
            xb[i] = pack2(dv * v.x, dv * v.y);
        } else xb[i] = 0;
    }
}

// ---------- coarse-bin histogram ----------
__global__ __launch_bounds__(P1_THREADS) void bin_hist(const int* __restrict__ dst,
                                                       int* __restrict__ binhist, int n) {
    __shared__ int hist[NBIN];
    int tid = threadIdx.x;
    if (tid < NBIN) hist[tid] = 0;
    __syncthreads();
    int base = blockIdx.x * P1_EPB;
#pragma unroll
    for (int j = 0; j < P1_EPT; j++) {
        int i = base + j * P1_THREADS + tid;
        if (i < n) atomicAdd(&hist[dst[i] / BINW], 1);
    }
    __syncthreads();
    if (tid < NBIN) {
        int v = hist[tid];
        if (v) atomicAdd(&binhist[tid], v);
    }
}

// ---------- scan 256 bin counts -> binoff (exclusive) + init bincur ----------
__global__ __launch_bounds__(NBIN) void bin_scan(const int* __restrict__ binhist,
                                                 int* __restrict__ binoff,
                                                 int* __restrict__ bincur) {
    __shared__ int buf[NBIN];
    int tid = threadIdx.x;
    int v = binhist[tid];
    buf[tid] = v;
    __syncthreads();
    for (int off = 1; off < NBIN; off <<= 1) {
        int t = (tid >= off) ? buf[tid - off] : 0;
        __syncthreads();
        buf[tid] += t;
        __syncthreads();
    }
    int ex = buf[tid] - v;
    binoff[tid] = ex;
    bincur[tid] = ex;
    if (tid == NBIN - 1) binoff[NBIN] = buf[tid];   // = NE
}

// pass 1: block-local counting-sort into 256 coarse bins; packed (src<<9)|localdst
__global__ __launch_bounds__(P1_THREADS) void scatter_pass1(const int* __restrict__ src,
                                                            const int* __restrict__ dst,
                                                            int* __restrict__ bincur,
                                                            uint* __restrict__ ebin, int n) {
    __shared__ int hist[NBIN];
    __shared__ int gbase[NBIN];
    int tid = threadIdx.x;
    if (tid < NBIN) hist[tid] = 0;
    __syncthreads();
    int base = blockIdx.x * P1_EPB;
    uint e[P1_EPT];
    int  rk[P1_EPT];
    int  bn[P1_EPT];
#pragma unroll
    for (int j = 0; j < P1_EPT; j++) {
        int i = base + j * P1_THREADS + tid;
        if (i < n) {
            int d = dst[i];
            int b = d / BINW;
            e[j] = ((uint)src[i] << 9) | (uint)(d - b * BINW);
            bn[j] = b;
            rk[j] = atomicAdd(&hist[b], 1);
        } else bn[j] = -1;
    }
    __syncthreads();
    if (tid < NBIN) gbase[tid] = hist[tid] ? atomicAdd(&bincur[tid], hist[tid]) : 0;
    __syncthreads();
#pragma unroll
    for (int j = 0; j < P1_EPT; j++)
        if (bn[j] >= 0) ebin[gbase[bn[j]] + rk[j]] = e[j];
}

// ---------- per-bin finalize: node hist -> dis + 8-aligned padded offsets/ends + scatter ----------
__global__ __launch_bounds__(256) void bin_finalize(const uint* __restrict__ ebin,
                                                    const int* __restrict__ binoff,
                                                    float* __restrict__ dis,
                                                    int* __restrict__ poffsets,
                                                    int* __restrict__ pends,
                                                    int* __restrict__ esrc) {
    __shared__ int hh[BINW];      // hist, then padded inclusive scan
    __shared__ int base_s[BINW];
    __shared__ int cur_s[BINW];
    int b = blockIdx.x;
    int tid = threadIdx.x;
    int v0 = b * BINW;
    int nv = min(BINW, NN - v0);
    int beg = binoff[b], end = binoff[b + 1];
    int pbase = ((beg + 7) & ~7) + PADW2 * b;      // 8-aligned closed-form bin base
    for (int i = tid; i < nv; i += 256) { hh[i] = 0; cur_s[i] = 0; }
    __syncthreads();
    for (int i = beg + tid; i < end; i += 256)
        atomicAdd(&hh[ebin[i] & 511u], 1);
    __syncthreads();
    int i1 = tid + 256;
    int c0 = (tid < nv) ? hh[tid] : 0;  int p0 = (c0 + 7) & ~7;
    int c1 = (i1 < nv) ? hh[i1] : 0;    int p1 = (c1 + 7) & ~7;
    __syncthreads();
    if (tid < nv) hh[tid] = p0;
    if (i1 < nv) hh[i1] = p1;
    __syncthreads();
    for (int off = 1; off < BINW; off <<= 1) {
        int t0 = (tid < nv && tid >= off) ? hh[tid - off] : 0;
        int t1 = (i1 < nv && i1 >= off) ? hh[i1 - off] : 0;
        __syncthreads();
        if (tid < nv) hh[tid] += t0;
        if (i1 < nv) hh[i1] += t1;
        __syncthreads();
    }
    if (tid < nv) {
        int base = pbase + hh[tid] - p0;
        base_s[tid] = base;
        poffsets[v0 + tid] = base;
        pends[v0 + tid] = base + p0;                         // exact padded end (no gap!)
        dis[v0 + tid] = rsqrtf((float)c0 + 1.0f);
        for (int j = c0; j < p0; j++) esrc[base + j] = NN;   // node tail padding
    }
    if (i1 < nv) {
        int base = pbase + hh[i1] - p1;
        base_s[i1] = base;
        poffsets[v0 + i1] = base;
        pends[v0 + i1] = base + p1;
        dis[v0 + i1] = rsqrtf((float)c1 + 1.0f);
        for (int j = c1; j < p1; j++) esrc[base + j] = NN;
    }
    // scatter (ebin region is L1/L2-hot from the hist pass)
    __syncthreads();
    for (int i = beg + tid; i < end; i += 256) {
        uint e = ebin[i];
        int l = (int)(e & 511u);
        int pos = base_s[l] + atomicAdd(&cur_s[l], 1);
        esrc[pos] = (int)(e >> 9);
    }
}

__global__ void build_wcat(const float* __restrict__ Wmu, const float* __restrict__ Wlv,
                           float* __restrict__ Wcat) {
    int i = blockIdx.x * blockDim.x + threadIdx.x;  // 128*64
    if (i < DHID * DO2) {
        int k = i >> 6, j = i & 63;
        Wcat[i] = (j < DOUT) ? Wmu[k * DOUT + j] : Wlv[k * DOUT + (j - DOUT)];
    }
}

// ---------- aggregateX: axb[v] = bf16( dis_v * (sum_e xsb[s] + xsb[v]) ), branch-free
__global__ __launch_bounds__(256) void aggregateX(const uint* __restrict__ xsb,  // bf16x2 [N+1,32]
                                                  const int* __restrict__ poffsets,
                                                  const int* __restrict__ pends,
                                                  const int* __restrict__ esrc,
                                                  const float* __restrict__ dis,
                                                  uint* __restrict__ axb) {
    int wave = threadIdx.x >> 6;
    int lane = threadIdx.x & 63;
    int oct  = lane >> 3;
    int j4   = (lane & 7) * 4;
    int v = blockIdx.x * 4 + wave;
    if (v >= NN) return;
    int beg = poffsets[v], end = pends[v];
    float a0 = 0.f, a1 = 0.f, a2 = 0.f, a3 = 0.f, a4 = 0.f, a5 = 0.f, a6 = 0.f, a7 = 0.f;
    for (int e0 = beg; e0 < end; e0 += 8) {
        int s = esrc[e0 + oct];
        uint4 p = *(const uint4*)(xsb + (size_t)s * 32 + j4);
        a0 += bflo(p.x); a1 += bfhi(p.x);
        a2 += bflo(p.y); a3 += bfhi(p.y);
        a4 += bflo(p.z); a5 += bfhi(p.z);
        a6 += bflo(p.w); a7 += bfhi(p.w);
    }
#pragma unroll
    for (int m = 8; m < 64; m <<= 1) {
        a0 += __shfl_xor(a0, m); a1 += __shfl_xor(a1, m);
        a2 += __shfl_xor(a2, m); a3 += __shfl_xor(a3, m);
        a4 += __shfl_xor(a4, m); a5 += __shfl_xor(a5, m);
        a6 += __shfl_xor(a6, m); a7 += __shfl_xor(a7, m);
    }
    uint4 pv = *(const uint4*)(xsb + (size_t)v * 32 + j4);   // self-loop (pre-scaled)
    a0 += bflo(pv.x); a1 += bfhi(pv.x);
    a2 += bflo(pv.y); a3 += bfhi(pv.y);
    a4 += bflo(pv.z); a5 += bfhi(pv.z);
    a6 += bflo(pv.w); a7 += bfhi(pv.w);
    if (lane < 8) {
        float dv = dis[v];
        uint4 o;
        o.x = pack2(dv * a0, dv * a1);
        o.y = pack2(dv * a2, dv * a3);
        o.z = pack2(dv * a4, dv * a5);
        o.w = pack2(dv * a6, dv * a7);
        *(uint4*)(axb + (size_t)v * 32 + j4) = o;
    }
}

__device__ __forceinline__ float selu_f(float v) {
    const float scale = 1.0507009873554805f;
    const float alpha = 1.6732632423543772f;
    return scale * (v > 0.f ? v : alpha * (expf(v) - 1.f));
}

// ---------- GEMM1: axb bf16[N,64] @ W1[64,128] + b1, selu -> h bf16[N,128] ----------
__global__ __launch_bounds__(256) void gemm1(const uint* __restrict__ axb,
                                             const float* __restrict__ W,
                                             const float* __restrict__ b,
                                             ushort* __restrict__ out) {
    __shared__ __align__(16) float xT[DIN][64];     // [k][row]  16 KB
    __shared__ __align__(16) float Ws[DIN][DHID];   // 32 KB
    __shared__ __align__(16) float Bs[DHID];
    int tid = threadIdx.x;
    int row0 = blockIdx.x * 64;

    for (int t = tid; t < (DIN * DHID) / 4; t += 256)
        ((float4*)Ws)[t] = ((const float4*)W)[t];
    if (tid < DHID / 4) ((float4*)Bs)[tid] = ((const float4*)b)[tid];

    int rr = tid & 63;
    int kq = tid >> 6;               // 0..3
    int grow = row0 + rr;
    for (int k0 = kq * 8; k0 < DIN; k0 += 32) {
        uint4 pv = make_uint4(0, 0, 0, 0);
        if (grow < NN) pv = *(const uint4*)(axb + (size_t)grow * 32 + k0 / 2);
        xT[k0 + 0][rr] = bflo(pv.x); xT[k0 + 1][rr] = bfhi(pv.x);
        xT[k0 + 2][rr] = bflo(pv.y); xT[k0 + 3][rr] = bfhi(pv.y);
        xT[k0 + 4][rr] = bflo(pv.z); xT[k0 + 5][rr] = bfhi(pv.z);
        xT[k0 + 6][rr] = bflo(pv.w); xT[k0 + 7][rr] = bfhi(pv.w);
    }
    __syncthreads();

    int tx = tid & 31;               // col group
    int ty = tid >> 5;               // 0..7 row group
    int c0 = tx * 4;
    int r0 = ty * 8;
    float acc[8][4];
#pragma unroll
    for (int i = 0; i < 8; i++)
#pragma unroll
        for (int j = 0; j < 4; j++) acc[i][j] = 0.f;

#pragma unroll 4
    for (int k = 0; k < DIN; k++) {
        float4 a0 = *(const float4*)&xT[k][r0];
        float4 a1 = *(const float4*)&xT[k][r0 + 4];
        float4 w  = *(const float4*)&Ws[k][c0];
        float av[8] = {a0.x, a0.y, a0.z, a0.w, a1.x, a1.y, a1.z, a1.w};
        float wv[4] = {w.x, w.y, w.z, w.w};
#pragma unroll
        for (int i = 0; i < 8; i++)
#pragma unroll
            for (int j = 0; j < 4; j++) acc[i][j] += av[i] * wv[j];
    }

    float4 bb = *(const float4*)&Bs[c0];
    float bv[4] = {bb.x, bb.y, bb.z, bb.w};
#pragma unroll
    for (int i = 0; i < 8; i++) {
        int orow = row0 + r0 + i;
        if (orow < NN) {
            float o0 = selu_f(acc[i][0] + bv[0]);
            float o1 = selu_f(acc[i][1] + bv[1]);
            float o2 = selu_f(acc[i][2] + bv[2]);
            float o3 = selu_f(acc[i][3] + bv[3]);
            *(uint2*)(out + (size_t)orow * DHID + c0) = make_uint2(pack2(o0, o1), pack2(o2, o3));
        }
    }
}

// ---------- GEMM2: h bf16[N,128] @ Wcat[128,64], epilogue *dis[v] -> hw2s bf16[N,64] ----------
__global__ __launch_bounds__(256) void gemm2(const ushort* __restrict__ h,
                                             const float* __restrict__ W,
                                             const float* __restrict__ dis,
                                             ushort* __restrict__ out) {
    __shared__ __align__(16) float hsT[DHID][64];   // [k][row] 32 KB
    __shared__ __align__(16) float Ws[DHID][DO2];   // 32 KB
    int tid = threadIdx.x;
    int row0 = blockIdx.x * 64;

    for (int t = tid; t < (DHID * DO2) / 4; t += 256)
        ((float4*)Ws)[t] = ((const float4*)W)[t];

    int rr = tid & 63;
    int kq = tid >> 6;               // 0..3
    int grow = row0 + rr;
    for (int k0 = kq * 8; k0 < DHID; k0 += 32) {
        uint4 pv = make_uint4(0, 0, 0, 0);
        if (grow < NN) pv = *(const uint4*)(h + (size_t)grow * DHID + k0);
        hsT[k0 + 0][rr] = bflo(pv.x); hsT[k0 + 1][rr] = bfhi(pv.x);
        hsT[k0 + 2][rr] = bflo(pv.y); hsT[k0 + 3][rr] = bfhi(pv.y);
        hsT[k0 + 4][rr] = bflo(pv.z); hsT[k0 + 5][rr] = bfhi(pv.z);
        hsT[k0 + 6][rr] = bflo(pv.w); hsT[k0 + 7][rr] = bfhi(pv.w);
    }
    __syncthreads();

    int tx = tid & 15;
    int ty = tid >> 4;               // 0..15
    int c0 = tx * 4;
    int r0 = ty * 4;
    float acc[4][4];
#pragma unroll
    for (int i = 0; i < 4; i++)
#pragma unroll
        for (int j = 0; j < 4; j++) acc[i][j] = 0.f;

#pragma unroll 4
    for (int k = 0; k < DHID; k++) {
        float4 a = *(const float4*)&hsT[k][r0];
        float4 w = *(const float4*)&Ws[k][c0];
        float av[4] = {a.x, a.y, a.z, a.w};
        float wv[4] = {w.x, w.y, w.z, w.w};
#pragma unroll
        for (int i = 0; i < 4; i++)
#pragma unroll
            for (int j = 0; j < 4; j++) acc[i][j] += av[i] * wv[j];
    }

#pragma unroll
    for (int i = 0; i < 4; i++) {
        int orow = row0 + r0 + i;
        if (orow < NN) {
            float dv = dis[orow];
            uint p0 = pack2(dv * acc[i][0], dv * acc[i][1]);
            uint p1 = pack2(dv * acc[i][2], dv * acc[i][3]);
            *(uint2*)(out + (size_t)orow * DO2 + c0) = make_uint2(p0, p1);
        }
    }
}

// ---------- aggregate2: branch-free padded sum; epilogue bias + mu/lv split ----------
__global__ __launch_bounds__(256) void aggregate2(const uint* __restrict__ hw2s, // bf16x2 [N+1,32]
                                                  const int* __restrict__ poffsets,
                                                  const int* __restrict__ pends,
                                                  const int* __restrict__ esrc,
                                                  const float* __restrict__ dis,
                                                  const float* __restrict__ bmu,
                                                  const float* __restrict__ blv,
                                                  float* __restrict__ out) {
    int wave = threadIdx.x >> 6;
    int lane = threadIdx.x & 63;
    int oct  = lane >> 3;
    int j4   = (lane & 7) * 4;
    int v = blockIdx.x * 4 + wave;
    if (v >= NN) return;
    int beg = poffsets[v], end = pends[v];
    float a0 = 0.f, a1 = 0.f, a2 = 0.f, a3 = 0.f, a4 = 0.f, a5 = 0.f, a6 = 0.f, a7 = 0.f;
    for (int e0 = beg; e0 < end; e0 += 8) {
        int s = esrc[e0 + oct];
        uint4 p = *(const uint4*)(hw2s + (size_t)s * 32 + j4);
        a0 += bflo(p.x); a1 += bfhi(p.x);
        a2 += bflo(p.y); a3 += bfhi(p.y);
        a4 += bflo(p.z); a5 += bfhi(p.z);
        a6 += bflo(p.w); a7 += bfhi(p.w);
    }
#pragma unroll
    for (int m = 8; m < 64; m <<= 1) {
        a0 += __shfl_xor(a0, m); a1 += __shfl_xor(a1, m);
        a2 += __shfl_xor(a2, m); a3 += __shfl_xor(a3, m);
        a4 += __shfl_xor(a4, m); a5 += __shfl_xor(a5, m);
        a6 += __shfl_xor(a6, m); a7 += __shfl_xor(a7, m);
    }
    uint4 pv = *(const uint4*)(hw2s + (size_t)v * 32 + j4);  // self-loop (pre-scaled)
    a0 += bflo(pv.x); a1 += bfhi(pv.x);
    a2 += bflo(pv.y); a3 += bfhi(pv.y);
    a4 += bflo(pv.z); a5 += bfhi(pv.z);
    a6 += bflo(pv.w); a7 += bfhi(pv.w);
    if (lane < 8) {
        float dv = dis[v];
        int j = lane;                          // 0..7: feats 8j..8j+7
        const float* bp = (j < 4) ? (bmu + 8 * j) : (blv + 8 * j - 32);
        float* op = (j < 4) ? (out + (size_t)v * DOUT + 8 * j)
                            : (out + (size_t)NN * DOUT + (size_t)v * DOUT + 8 * j - 32);
        float4 b0 = *(const float4*)bp;
        float4 b1 = *(const float4*)(bp + 4);
        *(float4*)op       = make_float4(dv * a0 + b0.x, dv * a1 + b0.y,
                                         dv * a2 + b0.z, dv * a3 + b0.w);
        *(float4*)(op + 4) = make_float4(dv * a4 + b1.x, dv * a5 + b1.y,
                                         dv * a6 + b1.z, dv * a7 + b1.w);
    }
}

extern "C" void kernel_launch(void* const* d_in, const int* in_sizes, int n_in,
                              void* d_out, int out_size, void* d_ws, size_t ws_size,
                              hipStream_t stream) {
    const float* x   = (const float*)d_in[0];
    const int*   ei  = (const int*)d_in[1];
    const int*   e_src = ei;            // edge_index[0]
    const int*   e_dst = ei + NE;       // edge_index[1]
    const float* W1  = (const float*)d_in[2];
    const float* b1  = (const float*)d_in[3];
    const float* Wmu = (const float*)d_in[4];
    const float* bmu = (const float*)d_in[5];
    const float* Wlv = (const float*)d_in[6];
    const float* blv = (const float*)d_in[7];
    float* out = (float*)d_out;

    char* ws = (char*)d_ws;
    size_t off = 0;
    auto alloc = [&](size_t bytes) -> void* {
        void* p = ws + off;
        off += (bytes + 255) & ~(size_t)255;
        return p;
    };
    int*    poffsets  = (int*)alloc((size_t)(NN + 1) * 4);
    int*    pends     = (int*)alloc((size_t)NN * 4);
    int*    esrc      = (int*)alloc((size_t)(NE + (size_t)PADW2 * NBIN + 64) * 4);
    int*    binhist   = (int*)alloc((size_t)NBIN * 4);
    int*    binoff    = (int*)alloc((size_t)(NBIN + 1) * 4);
    int*    bincur    = (int*)alloc((size_t)NBIN * 4);
    float*  dis       = (float*)alloc((size_t)NN * 4);
    float*  Wcat      = (float*)alloc((size_t)DHID * DO2 * 4);
    uint*   xb        = (uint*)alloc((size_t)(NN + 1) * 32 * 4);  // bf16 dis*x + zero row
    uint*   axb       = (uint*)alloc((size_t)NN * 32 * 4);        // bf16 A·x
    ushort* h         = (ushort*)alloc((size_t)NN * DHID * 2);    // bf16 h
    uint*   hw2s      = xb;            // xb dead after aggregateX; row NN stays zero
    uint*   ebin      = (uint*)h;      // h unused until gemm1; 5 MB <= 25.6 MB

    int p1blocks = (NE + P1_EPB - 1) / P1_EPB;
    zero_arr<<<1, NBIN, 0, stream>>>(binhist, NBIN);
    bin_hist<<<p1blocks, P1_THREADS, 0, stream>>>(e_dst, binhist, NE);
    bin_scan<<<1, NBIN, 0, stream>>>(binhist, binoff, bincur);
    scatter_pass1<<<p1blocks, P1_THREADS, 0, stream>>>(e_src, e_dst, bincur, ebin, NE);
    bin_finalize<<<NBIN, 256, 0, stream>>>(ebin, binoff, dis, poffsets, pends, esrc);
    build_wcat<<<(DHID * DO2 + 255) / 256, 256, 0, stream>>>(Wmu, Wlv, Wcat);
    cast_x<<<(((NN + 1) * 32) + 255) / 256, 256, 0, stream>>>(x, dis, xb, (NN + 1) * 32);

    int gblocks = (NN + 63) / 64;
    aggregateX<<<(NN + 3) / 4, 256, 0, stream>>>(xb, poffsets, pends, esrc, dis, axb);
    gemm1<<<gblocks, 256, 0, stream>>>(axb, W1, b1, h);
    gemm2<<<gblocks, 256, 0, stream>>>(h, Wcat, dis, (ushort*)hw2s);
    aggregate2<<<(NN + 3) / 4, 256, 0, stream>>>(hw2s, poffsets, pends, esrc, dis, bmu, blv, out);
}